// Round 7
// baseline (529.248 us; speedup 1.0000x reference)
//
#include <hip/hip_runtime.h>
#include <hip/hip_bf16.h>

#define DEPTH   6
#define NLEAF   64
#define BATCH   1024
#define DIM     256
#define NTREES  512
#define UNITS   16
#define NCOLS   (NTREES*DEPTH)          // 3072

// ---- GEMM: 64x64 tile, 256 threads, micro 4x4, KCH=32, LDS double-buffer ----
#define TM    64
#define TN    64
#define KCH   32
#define APAD  36                         // la[row][k] stride (36%32=4 -> rows spread banks)
#define BPAD  68                         // lb[k][col] stride (68%32=4)
#define MB    (BATCH/TM)                 // 16
#define NB    (NCOLS/TN)                 // 48
#define NKC   (DIM/KCH)                  // 8

// ---- tree kernel ----
#define TPT   4                          // trees per thread
#define NTG   (NTREES/TPT)               // 128

// ws layout (floats): gates 12.6MB | thrp | selp/partial overlay (~21 MB total,
// proven to fit: round-5 primary path executed)
#define WS_GATES 0
#define WS_THRP  (WS_GATES + BATCH*NCOLS)
#define WS_SH    (WS_THRP + NCOLS)

// ---------------------------------------------------------------------------
// prep: sparsemax over depth axis of (dim, n_trees, depth), scaled by
// exp(-log_temp); tail block computes thrp = thr * exp(-log_temp).
// ---------------------------------------------------------------------------
__global__ void prep_kernel(const float* __restrict__ fsl,
                            const float* __restrict__ thr,
                            const float* __restrict__ lt,
                            float* __restrict__ selp,
                            float* __restrict__ thrp) {
    if (blockIdx.x == (DIM * NTREES) / 256) {          // tail: thrp
        for (int j = threadIdx.x; j < NCOLS; j += 256)
            thrp[j] = thr[j] * __expf(-lt[j]);
        return;
    }
    int t = blockIdx.x * 256 + threadIdx.x;            // t = i*NTREES + n
    int n = t & (NTREES - 1);
    int base = t * DEPTH;

    float zv[DEPTH], zs[DEPTH];
#pragma unroll
    for (int d = 0; d < DEPTH; ++d) { zv[d] = fsl[base + d]; zs[d] = zv[d]; }

#pragma unroll
    for (int p = 0; p < DEPTH - 1; ++p)
#pragma unroll
        for (int j = 0; j < DEPTH - 1 - p; ++j) {
            float a = zs[j], b = zs[j + 1];
            zs[j] = fmaxf(a, b); zs[j + 1] = fminf(a, b);
        }

    float cs[DEPTH];
    cs[0] = zs[0];
#pragma unroll
    for (int d = 1; d < DEPTH; ++d) cs[d] = cs[d - 1] + zs[d];

    int k = 0;
#pragma unroll
    for (int d = 0; d < DEPTH; ++d)
        if (zs[d] * (float)(d + 1) > cs[d] - 1.0f) k++;

    float csk = cs[0];
#pragma unroll
    for (int d = 0; d < DEPTH; ++d) csk = (k - 1 == d) ? cs[d] : csk;
    float tau = (csk - 1.0f) / (float)k;

#pragma unroll
    for (int d = 0; d < DEPTH; ++d) {
        float it = __expf(-lt[n * DEPTH + d]);
        selp[base + d] = fmaxf(zv[d] - tau, 0.0f) * it;
    }
}

// ---------------------------------------------------------------------------
// gemm_gates v2: gates = sparsemoid( x @ selp - thrp )
// 256 threads, 64x64 tile, micro 4x4, KCH=32, double-buffered LDS.
// Staging regs (4 x float4) live only across the compute phase; launch_bounds
// (256,4) pins VGPR<=128 -> 16 waves/CU cap (grid supplies 12/CU).
// Hot ds_reads verified <=2-way bank aliasing (free).
// ---------------------------------------------------------------------------
__global__ __launch_bounds__(256, 4)
void gemm_gates(const float* __restrict__ x,
                const float* __restrict__ selp,
                const float* __restrict__ thrp,
                float* __restrict__ gates) {
    __shared__ float la[2][TM * APAD];   // [buf][row][k]   9.2 KB each
    __shared__ float lb[2][KCH * BPAD];  // [buf][k][col]   8.7 KB each

    const int tid = threadIdx.x;
    const int n0  = blockIdx.x * TN;
    const int m0  = blockIdx.y * TM;
    const int tx  = tid & 15;            // col group (4 cols)
    const int ty  = tid >> 4;            // row group (4 rows)

    float acc[4][4];
#pragma unroll
    for (int r = 0; r < 4; ++r)
#pragma unroll
        for (int c = 0; c < 4; ++c) acc[r][c] = 0.0f;

    float4 ra[2], rb[2];                 // transient staging (16 VGPR)

#define STAGE(KC_)                                                             \
    _Pragma("unroll")                                                          \
    for (int j = 0; j < 2; ++j) {                                              \
        int f = tid + j * 256;                                                 \
        ra[j] = *(const float4*)&x[(m0 + (f >> 3)) * DIM + (KC_) * KCH + (f & 7) * 4]; \
        rb[j] = *(const float4*)&selp[((KC_) * KCH + (f >> 4)) * NCOLS + n0 + (f & 15) * 4]; \
    }
#define COMMIT(P_)                                                             \
    _Pragma("unroll")                                                          \
    for (int j = 0; j < 2; ++j) {                                              \
        int f = tid + j * 256;                                                 \
        *(float4*)&la[P_][(f >> 3) * APAD + (f & 7) * 4] = ra[j];              \
        *(float4*)&lb[P_][(f >> 4) * BPAD + (f & 15) * 4] = rb[j];             \
    }

    STAGE(0)
    COMMIT(0)
    __syncthreads();

    for (int kc = 0; kc < NKC; ++kc) {
        const int par = kc & 1;
        if (kc < NKC - 1) STAGE(kc + 1)  // issue early: HBM/L2 latency hides under FMAs

#pragma unroll
        for (int kk = 0; kk < KCH; kk += 4) {
            float a4[4][4], b4[4][4];
#pragma unroll
            for (int r = 0; r < 4; ++r)
                *(float4*)a4[r] = *(const float4*)&la[par][(ty * 4 + r) * APAD + kk];
#pragma unroll
            for (int j = 0; j < 4; ++j)
                *(float4*)b4[j] = *(const float4*)&lb[par][(kk + j) * BPAD + tx * 4];
#pragma unroll
            for (int j = 0; j < 4; ++j)
#pragma unroll
                for (int r = 0; r < 4; ++r)
#pragma unroll
                    for (int c = 0; c < 4; ++c)
                        acc[r][c] = fmaf(a4[r][j], b4[j][c], acc[r][c]);
        }

        if (kc < NKC - 1) {
            COMMIT(par ^ 1)              // other buffer: no read-write hazard
            __syncthreads();             // one barrier per K-chunk
        }
    }
#undef STAGE
#undef COMMIT

    // epilogue: sparsemoid + store
    float4 th4 = *(const float4*)&thrp[n0 + tx * 4];
    float th[4] = {th4.x, th4.y, th4.z, th4.w};
#pragma unroll
    for (int r = 0; r < 4; ++r) {
        float o[4];
#pragma unroll
        for (int c = 0; c < 4; ++c) {
            float tl = acc[r][c] - th[c];
            o[c] = fminf(fmaxf(fmaf(0.5f, tl, 0.5f), 0.0f), 1.0f);
        }
        *(float4*)&gates[(size_t)(m0 + ty * 4 + r) * NCOLS + n0 + tx * 4] = *(float4*)&o[0];
    }
}

// ---------------------------------------------------------------------------
// tree_kernel v2: pure-register, no LDS/barriers. resp read via float4
// (wave-uniform addr -> scalarizable; bounded cost even as v-loads).
// Per-tree g loads keep VGPR ~100 so launch_bounds(256,4) holds without spill.
// bc = bid&7 pins each XCD to one gates slice (1.5MB) + resp (2MB) < 4MB L2.
// ---------------------------------------------------------------------------
__global__ __launch_bounds__(256, 4)
void tree_kernel(const float* __restrict__ gates,
                 const float* __restrict__ resp,
                 float* __restrict__ partial) {
    const int bid  = blockIdx.x;
    const int bc   = bid & 7;                          // batch slice (XCD-pinned)
    const int tg   = bid >> 3;                         // tree group 0..127
    const int tid  = threadIdx.x;
    const int uh   = __builtin_amdgcn_readfirstlane((tid >> 6) & 1);
    const int b    = bc * 128 + (tid >> 7) * 64 + (tid & 63);

    const float* gp = gates + (size_t)b * NCOLS + tg * (TPT * DEPTH);

    float out8[8];
#pragma unroll
    for (int u = 0; u < 8; ++u) out8[u] = 0.0f;

#pragma unroll
    for (int t = 0; t < TPT; ++t) {
        // per-tree gate load: 3x float2 (8B-aligned at t*24B)
        float g[DEPTH];
#pragma unroll
        for (int i = 0; i < 3; ++i)
            *(float2*)&g[i * 2] = *(const float2*)&gp[t * DEPTH + i * 2];

        // leaf probabilities, fully static indexing
        float p[NLEAF];
        p[0] = 1.0f;
#pragma unroll
        for (int d = 0; d < DEPTH; ++d) {
            int w = 1 << d;
            float gd = g[d], hd = 1.0f - gd;
#pragma unroll
            for (int c = w - 1; c >= 0; --c) {
                float base = p[c];
                p[c + w] = base * hd;
                p[c]     = base * gd;
            }
        }

        // response matvec: wave-uniform float4 loads, 2-way ILP accumulators
        const float4* rp4 = (const float4*)(resp +
            (size_t)((tg * TPT + t) * UNITS + uh * 8) * NLEAF);
#pragma unroll
        for (int u = 0; u < 8; ++u) {
            float s0 = 0.0f, s1 = 0.0f;
#pragma unroll
            for (int c4 = 0; c4 < 16; c4 += 2) {
                float4 r0 = rp4[u * 16 + c4];
                float4 r1 = rp4[u * 16 + c4 + 1];
                s0 = fmaf(p[c4 * 4 + 0], r0.x, s0);
                s0 = fmaf(p[c4 * 4 + 1], r0.y, s0);
                s0 = fmaf(p[c4 * 4 + 2], r0.z, s0);
                s0 = fmaf(p[c4 * 4 + 3], r0.w, s0);
                s1 = fmaf(p[c4 * 4 + 4], r1.x, s1);
                s1 = fmaf(p[c4 * 4 + 5], r1.y, s1);
                s1 = fmaf(p[c4 * 4 + 6], r1.z, s1);
                s1 = fmaf(p[c4 * 4 + 7], r1.w, s1);
            }
            out8[u] += s0 + s1;
        }
    }

    float* pp = partial + ((size_t)tg * BATCH + b) * UNITS + uh * 8;
    *(float4*)&pp[0] = *(float4*)&out8[0];
    *(float4*)&pp[4] = *(float4*)&out8[4];
}

// ---------------------------------------------------------------------------
// reduce over NTG partials, scale 1/NTREES. 1 wave/CU -> needs load ILP.
// ---------------------------------------------------------------------------
__global__ void reduce_kernel(const float* __restrict__ partial,
                              float* __restrict__ out) {
    int idx = blockIdx.x * 256 + threadIdx.x;          // 0..16383
    float s = 0.0f;
#pragma unroll 16
    for (int tg = 0; tg < NTG; ++tg)
        s += partial[(size_t)tg * BATCH * UNITS + idx];
    out[idx] = s * (1.0f / (float)NTREES);
}

// ---------------------------------------------------------------------------
extern "C" void kernel_launch(void* const* d_in, const int* in_sizes, int n_in,
                              void* d_out, int out_size, void* d_ws, size_t ws_size,
                              hipStream_t stream) {
    const float* x    = (const float*)d_in[0];
    const float* fsl  = (const float*)d_in[1];
    const float* thr  = (const float*)d_in[2];
    const float* lt   = (const float*)d_in[3];
    const float* resp = (const float*)d_in[4];
    float* out = (float*)d_out;
    float* ws  = (float*)d_ws;

    float* gates   = ws + WS_GATES;
    float* thrp    = ws + WS_THRP;
    float* selp    = ws + WS_SH;     // lifetime: prep -> gemm
    float* partial = ws + WS_SH;     // lifetime: tree -> reduce (overlay)

    prep_kernel<<<(DIM * NTREES) / 256 + 1, 256, 0, stream>>>(fsl, thr, lt, selp, thrp);
    gemm_gates<<<dim3(NB, MB), 256, 0, stream>>>(x, selp, thrp, gates);
    tree_kernel<<<NTG * 8, 256, 0, stream>>>(gates, resp, partial);
    reduce_kernel<<<(BATCH * UNITS) / 256, 256, 0, stream>>>(partial, out);
}

// Round 8
// 225.561 us; speedup vs baseline: 2.3464x; 2.3464x over previous
//
#include <hip/hip_runtime.h>
#include <hip/hip_bf16.h>

#define DEPTH   6
#define NLEAF   64
#define BATCH   1024
#define DIM     256
#define NTREES  512
#define UNITS   16
#define NCOLS   (NTREES*DEPTH)          // 3072

// ---- GEMM: 64x64 tile, 256 threads, micro 4x4, KCH=32, LDS double-buffer ----
#define TM    64
#define TN    64
#define KCH   32
#define APAD  36                         // la[row][k] stride (36%32=4 -> rows spread banks)
#define BPAD  68                         // lb[k][col] stride (68%32=4)
#define MB    (BATCH/TM)                 // 16
#define NB    (NCOLS/TN)                 // 48
#define NKC   (DIM/KCH)                  // 8

// ---- tree kernel ----
#define TPT   4                          // trees per thread
#define NTG   (NTREES/TPT)               // 128

// ws layout (floats): gates 12.6MB | thrp | selp/partial overlay (~21 MB total)
#define WS_GATES 0
#define WS_THRP  (WS_GATES + BATCH*NCOLS)
#define WS_SH    (WS_THRP + NCOLS)

// ---------------------------------------------------------------------------
// prep: sparsemax over depth axis of (dim, n_trees, depth), scaled by
// exp(-log_temp); tail block computes thrp = thr * exp(-log_temp).
// ---------------------------------------------------------------------------
__global__ void prep_kernel(const float* __restrict__ fsl,
                            const float* __restrict__ thr,
                            const float* __restrict__ lt,
                            float* __restrict__ selp,
                            float* __restrict__ thrp) {
    if (blockIdx.x == (DIM * NTREES) / 256) {          // tail: thrp
        for (int j = threadIdx.x; j < NCOLS; j += 256)
            thrp[j] = thr[j] * __expf(-lt[j]);
        return;
    }
    int t = blockIdx.x * 256 + threadIdx.x;            // t = i*NTREES + n
    int n = t & (NTREES - 1);
    int base = t * DEPTH;

    float zv[DEPTH], zs[DEPTH];
#pragma unroll
    for (int d = 0; d < DEPTH; ++d) { zv[d] = fsl[base + d]; zs[d] = zv[d]; }

#pragma unroll
    for (int p = 0; p < DEPTH - 1; ++p)
#pragma unroll
        for (int j = 0; j < DEPTH - 1 - p; ++j) {
            float a = zs[j], b = zs[j + 1];
            zs[j] = fmaxf(a, b); zs[j + 1] = fminf(a, b);
        }

    float cs[DEPTH];
    cs[0] = zs[0];
#pragma unroll
    for (int d = 1; d < DEPTH; ++d) cs[d] = cs[d - 1] + zs[d];

    int k = 0;
#pragma unroll
    for (int d = 0; d < DEPTH; ++d)
        if (zs[d] * (float)(d + 1) > cs[d] - 1.0f) k++;

    float csk = cs[0];
#pragma unroll
    for (int d = 0; d < DEPTH; ++d) csk = (k - 1 == d) ? cs[d] : csk;
    float tau = (csk - 1.0f) / (float)k;

#pragma unroll
    for (int d = 0; d < DEPTH; ++d) {
        float it = __expf(-lt[n * DEPTH + d]);
        selp[base + d] = fmaxf(zv[d] - tau, 0.0f) * it;
    }
}

// ---------------------------------------------------------------------------
// gemm_gates: gates = sparsemoid( x @ selp - thrp )
// 256 threads, 64x64 tile, micro 4x4, KCH=32, double-buffered LDS.
// launch_bounds(256,2): round-7 showed (256,4) clamps VGPR to 64 on this
// compiler -> 1.05 GB scratch spill traffic, 345 us. (256,2) caps at 128+
// (demand ~90) -> no spill. Grid supplies 12 waves/CU regardless.
// Hot ds_reads verified <=2-way bank aliasing (free); measured conflicts = 0.
// ---------------------------------------------------------------------------
__global__ __launch_bounds__(256, 2)
void gemm_gates(const float* __restrict__ x,
                const float* __restrict__ selp,
                const float* __restrict__ thrp,
                float* __restrict__ gates) {
    __shared__ float la[2][TM * APAD];   // [buf][row][k]   9.2 KB each
    __shared__ float lb[2][KCH * BPAD];  // [buf][k][col]   8.7 KB each

    const int tid = threadIdx.x;
    const int n0  = blockIdx.x * TN;
    const int m0  = blockIdx.y * TM;
    const int tx  = tid & 15;            // col group (4 cols)
    const int ty  = tid >> 4;            // row group (4 rows)

    float acc[4][4];
#pragma unroll
    for (int r = 0; r < 4; ++r)
#pragma unroll
        for (int c = 0; c < 4; ++c) acc[r][c] = 0.0f;

    float4 ra[2], rb[2];                 // transient staging (16 VGPR)

#define STAGE(KC_)                                                             \
    _Pragma("unroll")                                                          \
    for (int j = 0; j < 2; ++j) {                                              \
        int f = tid + j * 256;                                                 \
        ra[j] = *(const float4*)&x[(m0 + (f >> 3)) * DIM + (KC_) * KCH + (f & 7) * 4]; \
        rb[j] = *(const float4*)&selp[((KC_) * KCH + (f >> 4)) * NCOLS + n0 + (f & 15) * 4]; \
    }
#define COMMIT(P_)                                                             \
    _Pragma("unroll")                                                          \
    for (int j = 0; j < 2; ++j) {                                              \
        int f = tid + j * 256;                                                 \
        *(float4*)&la[P_][(f >> 3) * APAD + (f & 7) * 4] = ra[j];              \
        *(float4*)&lb[P_][(f >> 4) * BPAD + (f & 15) * 4] = rb[j];             \
    }

    STAGE(0)
    COMMIT(0)
    __syncthreads();

    for (int kc = 0; kc < NKC; ++kc) {
        const int par = kc & 1;
        if (kc < NKC - 1) STAGE(kc + 1)  // issue early: HBM/L2 latency hides under FMAs

#pragma unroll
        for (int kk = 0; kk < KCH; kk += 4) {
            float a4[4][4], b4[4][4];
#pragma unroll
            for (int r = 0; r < 4; ++r)
                *(float4*)a4[r] = *(const float4*)&la[par][(ty * 4 + r) * APAD + kk];
#pragma unroll
            for (int j = 0; j < 4; ++j)
                *(float4*)b4[j] = *(const float4*)&lb[par][(kk + j) * BPAD + tx * 4];
#pragma unroll
            for (int j = 0; j < 4; ++j)
#pragma unroll
                for (int r = 0; r < 4; ++r)
#pragma unroll
                    for (int c = 0; c < 4; ++c)
                        acc[r][c] = fmaf(a4[r][j], b4[j][c], acc[r][c]);
        }

        if (kc < NKC - 1) {
            COMMIT(par ^ 1)              // other buffer: no read-write hazard
            __syncthreads();             // one barrier per K-chunk
        }
    }
#undef STAGE
#undef COMMIT

    // epilogue: sparsemoid + store
    float4 th4 = *(const float4*)&thrp[n0 + tx * 4];
    float th[4] = {th4.x, th4.y, th4.z, th4.w};
#pragma unroll
    for (int r = 0; r < 4; ++r) {
        float o[4];
#pragma unroll
        for (int c = 0; c < 4; ++c) {
            float tl = acc[r][c] - th[c];
            o[c] = fminf(fmaxf(fmaf(0.5f, tl, 0.5f), 0.0f), 1.0f);
        }
        *(float4*)&gates[(size_t)(m0 + ty * 4 + r) * NCOLS + n0 + tx * 4] = *(float4*)&o[0];
    }
}

// ---------------------------------------------------------------------------
// tree_kernel: pure-register, no LDS/barriers. resp read via float4 from a
// wave-uniform address (readfirstlane'd uh) -> scalarizable to s_load.
// launch_bounds(256,2): p[64] + out8 + misc ~ 95 VGPR demand; (256,4)'s
// 64-VGPR clamp would spill (round-7 lesson).
// bc = bid&7 pins each XCD to one gates slice (1.5MB) + resp (2MB) < 4MB L2.
// ---------------------------------------------------------------------------
__global__ __launch_bounds__(256, 2)
void tree_kernel(const float* __restrict__ gates,
                 const float* __restrict__ resp,
                 float* __restrict__ partial) {
    const int bid  = blockIdx.x;
    const int bc   = bid & 7;                          // batch slice (XCD-pinned)
    const int tg   = bid >> 3;                         // tree group 0..127
    const int tid  = threadIdx.x;
    const int uh   = __builtin_amdgcn_readfirstlane((tid >> 6) & 1);
    const int b    = bc * 128 + (tid >> 7) * 64 + (tid & 63);

    const float* gp = gates + (size_t)b * NCOLS + tg * (TPT * DEPTH);

    float out8[8];
#pragma unroll
    for (int u = 0; u < 8; ++u) out8[u] = 0.0f;

#pragma unroll
    for (int t = 0; t < TPT; ++t) {
        // per-tree gate load: 3x float2 (8B-aligned at t*24B)
        float g[DEPTH];
#pragma unroll
        for (int i = 0; i < 3; ++i)
            *(float2*)&g[i * 2] = *(const float2*)&gp[t * DEPTH + i * 2];

        // leaf probabilities, fully static indexing
        float p[NLEAF];
        p[0] = 1.0f;
#pragma unroll
        for (int d = 0; d < DEPTH; ++d) {
            int w = 1 << d;
            float gd = g[d], hd = 1.0f - gd;
#pragma unroll
            for (int c = w - 1; c >= 0; --c) {
                float base = p[c];
                p[c + w] = base * hd;
                p[c]     = base * gd;
            }
        }

        // response matvec: wave-uniform float4 loads, 2-way ILP accumulators
        const float4* rp4 = (const float4*)(resp +
            (size_t)((tg * TPT + t) * UNITS + uh * 8) * NLEAF);
#pragma unroll
        for (int u = 0; u < 8; ++u) {
            float s0 = 0.0f, s1 = 0.0f;
#pragma unroll
            for (int c4 = 0; c4 < 16; c4 += 2) {
                float4 r0 = rp4[u * 16 + c4];
                float4 r1 = rp4[u * 16 + c4 + 1];
                s0 = fmaf(p[c4 * 4 + 0], r0.x, s0);
                s0 = fmaf(p[c4 * 4 + 1], r0.y, s0);
                s0 = fmaf(p[c4 * 4 + 2], r0.z, s0);
                s0 = fmaf(p[c4 * 4 + 3], r0.w, s0);
                s1 = fmaf(p[c4 * 4 + 4], r1.x, s1);
                s1 = fmaf(p[c4 * 4 + 5], r1.y, s1);
                s1 = fmaf(p[c4 * 4 + 6], r1.z, s1);
                s1 = fmaf(p[c4 * 4 + 7], r1.w, s1);
            }
            out8[u] += s0 + s1;
        }
    }

    float* pp = partial + ((size_t)tg * BATCH + b) * UNITS + uh * 8;
    *(float4*)&pp[0] = *(float4*)&out8[0];
    *(float4*)&pp[4] = *(float4*)&out8[4];
}

// ---------------------------------------------------------------------------
// reduce over NTG partials, scale 1/NTREES. 1 wave/CU -> needs load ILP.
// ---------------------------------------------------------------------------
__global__ void reduce_kernel(const float* __restrict__ partial,
                              float* __restrict__ out) {
    int idx = blockIdx.x * 256 + threadIdx.x;          // 0..16383
    float s = 0.0f;
#pragma unroll 16
    for (int tg = 0; tg < NTG; ++tg)
        s += partial[(size_t)tg * BATCH * UNITS + idx];
    out[idx] = s * (1.0f / (float)NTREES);
}

// ---------------------------------------------------------------------------
extern "C" void kernel_launch(void* const* d_in, const int* in_sizes, int n_in,
                              void* d_out, int out_size, void* d_ws, size_t ws_size,
                              hipStream_t stream) {
    const float* x    = (const float*)d_in[0];
    const float* fsl  = (const float*)d_in[1];
    const float* thr  = (const float*)d_in[2];
    const float* lt   = (const float*)d_in[3];
    const float* resp = (const float*)d_in[4];
    float* out = (float*)d_out;
    float* ws  = (float*)d_ws;

    float* gates   = ws + WS_GATES;
    float* thrp    = ws + WS_THRP;
    float* selp    = ws + WS_SH;     // lifetime: prep -> gemm
    float* partial = ws + WS_SH;     // lifetime: tree -> reduce (overlay)

    prep_kernel<<<(DIM * NTREES) / 256 + 1, 256, 0, stream>>>(fsl, thr, lt, selp, thrp);
    gemm_gates<<<dim3(NB, MB), 256, 0, stream>>>(x, selp, thrp, gates);
    tree_kernel<<<NTG * 8, 256, 0, stream>>>(gates, resp, partial);
    reduce_kernel<<<(BATCH * UNITS) / 256, 256, 0, stream>>>(partial, out);
}

// Round 9
// 191.780 us; speedup vs baseline: 2.7597x; 1.1761x over previous
//
#include <hip/hip_runtime.h>
#include <hip/hip_bf16.h>

#define DEPTH   6
#define NLEAF   64
#define BATCH   1024
#define DIM     256
#define NTREES  512
#define UNITS   16
#define NCOLS   (NTREES*DEPTH)          // 3072

// ---- GEMM: LDS-free. wave = 16 rows x 64 cols; A via s_load (row uniform),
// ---- B via coalesced vector loads (col = lane). 768 blocks.
#define GROWS 32                         // rows per block (2 wave-rows of 16)
#define GCOLS 128                        // cols per block (2 wave-cols of 64)
#define GKCH  32

// ---- tree kernel ----
#define TPT   4                          // trees per thread
#define NTG   (NTREES/TPT)               // 128

// ws layout (floats): gates 12.6MB | thrp | selp/partial overlay (~21 MB total)
#define WS_GATES 0
#define WS_THRP  (WS_GATES + BATCH*NCOLS)
#define WS_SH    (WS_THRP + NCOLS)

// ---------------------------------------------------------------------------
// prep: sparsemax over depth axis of (dim, n_trees, depth), scaled by
// exp(-log_temp); tail block computes thrp = thr * exp(-log_temp).
// ---------------------------------------------------------------------------
__global__ void prep_kernel(const float* __restrict__ fsl,
                            const float* __restrict__ thr,
                            const float* __restrict__ lt,
                            float* __restrict__ selp,
                            float* __restrict__ thrp) {
    if (blockIdx.x == (DIM * NTREES) / 256) {          // tail: thrp
        for (int j = threadIdx.x; j < NCOLS; j += 256)
            thrp[j] = thr[j] * __expf(-lt[j]);
        return;
    }
    int t = blockIdx.x * 256 + threadIdx.x;            // t = i*NTREES + n
    int n = t & (NTREES - 1);
    int base = t * DEPTH;

    float zv[DEPTH], zs[DEPTH];
#pragma unroll
    for (int d = 0; d < DEPTH; ++d) { zv[d] = fsl[base + d]; zs[d] = zv[d]; }

#pragma unroll
    for (int p = 0; p < DEPTH - 1; ++p)
#pragma unroll
        for (int j = 0; j < DEPTH - 1 - p; ++j) {
            float a = zs[j], b = zs[j + 1];
            zs[j] = fmaxf(a, b); zs[j + 1] = fminf(a, b);
        }

    float cs[DEPTH];
    cs[0] = zs[0];
#pragma unroll
    for (int d = 1; d < DEPTH; ++d) cs[d] = cs[d - 1] + zs[d];

    int k = 0;
#pragma unroll
    for (int d = 0; d < DEPTH; ++d)
        if (zs[d] * (float)(d + 1) > cs[d] - 1.0f) k++;

    float csk = cs[0];
#pragma unroll
    for (int d = 0; d < DEPTH; ++d) csk = (k - 1 == d) ? cs[d] : csk;
    float tau = (csk - 1.0f) / (float)k;

#pragma unroll
    for (int d = 0; d < DEPTH; ++d) {
        float it = __expf(-lt[n * DEPTH + d]);
        selp[base + d] = fmaxf(zv[d] - tau, 0.0f) * it;
    }
}

// ---------------------------------------------------------------------------
// gemm_gates v3: LDS-FREE. gates = sparsemoid( x @ selp - thrp ).
// Wave-uniform rows -> A loads scalarize to s_load; inner loop is
// v_fmac acc[r], s_a[k], v_b[k]. Lane-indexed cols -> B loads coalesce
// (256B/instr, L2-resident). No LDS, no barriers, no spill (~60 VGPR).
// Grid (32 row-blocks, 24 col-panels): XCD round-robin on blockIdx.x keeps
// one col-panel's B inside one XCD L2.
// ---------------------------------------------------------------------------
__global__ void gemm_gates(const float* __restrict__ x,
                           const float* __restrict__ selp,
                           const float* __restrict__ thrp,
                           float* __restrict__ gates) {
    const int tid  = threadIdx.x;
    const int lane = tid & 63;
    const int w    = __builtin_amdgcn_readfirstlane(tid >> 6);   // wave 0..3
    const int m0   = blockIdx.x * GROWS + (w >> 1) * 16;         // wave's rows
    const int col  = blockIdx.y * GCOLS + (w & 1) * 64 + lane;   // lane's col

    float acc[16];
#pragma unroll
    for (int r = 0; r < 16; ++r) acc[r] = 0.0f;

    for (int kc = 0; kc < DIM; kc += GKCH) {
        // B chunk: 32 coalesced lane-loads (32 VGPR)
        float b[GKCH];
#pragma unroll
        for (int k = 0; k < GKCH; ++k)
            b[k] = selp[(size_t)(kc + k) * NCOLS + col];

        // A rows: wave-uniform address -> s_load; FMA with SGPR operand
#pragma unroll
        for (int r = 0; r < 16; ++r) {
            const float* ap = &x[(size_t)(m0 + r) * DIM + kc];
#pragma unroll
            for (int k = 0; k < GKCH; ++k)
                acc[r] = fmaf(ap[k], b[k], acc[r]);
        }
    }

    // epilogue: sparsemoid + coalesced store
    const float th = thrp[col];
#pragma unroll
    for (int r = 0; r < 16; ++r) {
        float tl = acc[r] - th;
        float g  = fminf(fmaxf(fmaf(0.5f, tl, 0.5f), 0.0f), 1.0f);
        gates[(size_t)(m0 + r) * NCOLS + col] = g;
    }
}

// ---------------------------------------------------------------------------
// tree_kernel: pure-register, no LDS/barriers. resp read via float4 from a
// wave-uniform address (readfirstlane'd uh) -> scalarizable to s_load.
// launch_bounds(256,2): 128-VGPR cap >= ~100 demand, no spill.
// bc = bid&7 pins each XCD to one gates slice (1.5MB) + resp (2MB) < 4MB L2.
// ---------------------------------------------------------------------------
__global__ __launch_bounds__(256, 2)
void tree_kernel(const float* __restrict__ gates,
                 const float* __restrict__ resp,
                 float* __restrict__ partial) {
    const int bid  = blockIdx.x;
    const int bc   = bid & 7;                          // batch slice (XCD-pinned)
    const int tg   = bid >> 3;                         // tree group 0..127
    const int tid  = threadIdx.x;
    const int uh   = __builtin_amdgcn_readfirstlane((tid >> 6) & 1);
    const int b    = bc * 128 + (tid >> 7) * 64 + (tid & 63);

    const float* gp = gates + (size_t)b * NCOLS + tg * (TPT * DEPTH);

    float out8[8];
#pragma unroll
    for (int u = 0; u < 8; ++u) out8[u] = 0.0f;

#pragma unroll
    for (int t = 0; t < TPT; ++t) {
        // per-tree gate load: 3x float2 (8B-aligned at t*24B)
        float g[DEPTH];
#pragma unroll
        for (int i = 0; i < 3; ++i)
            *(float2*)&g[i * 2] = *(const float2*)&gp[t * DEPTH + i * 2];

        // leaf probabilities, fully static indexing
        float p[NLEAF];
        p[0] = 1.0f;
#pragma unroll
        for (int d = 0; d < DEPTH; ++d) {
            int w = 1 << d;
            float gd = g[d], hd = 1.0f - gd;
#pragma unroll
            for (int c = w - 1; c >= 0; --c) {
                float base = p[c];
                p[c + w] = base * hd;
                p[c]     = base * gd;
            }
        }

        // response matvec: wave-uniform float4 loads, 2-way ILP accumulators
        const float4* rp4 = (const float4*)(resp +
            (size_t)((tg * TPT + t) * UNITS + uh * 8) * NLEAF);
#pragma unroll
        for (int u = 0; u < 8; ++u) {
            float s0 = 0.0f, s1 = 0.0f;
#pragma unroll
            for (int c4 = 0; c4 < 16; c4 += 2) {
                float4 r0 = rp4[u * 16 + c4];
                float4 r1 = rp4[u * 16 + c4 + 1];
                s0 = fmaf(p[c4 * 4 + 0], r0.x, s0);
                s0 = fmaf(p[c4 * 4 + 1], r0.y, s0);
                s0 = fmaf(p[c4 * 4 + 2], r0.z, s0);
                s0 = fmaf(p[c4 * 4 + 3], r0.w, s0);
                s1 = fmaf(p[c4 * 4 + 4], r1.x, s1);
                s1 = fmaf(p[c4 * 4 + 5], r1.y, s1);
                s1 = fmaf(p[c4 * 4 + 6], r1.z, s1);
                s1 = fmaf(p[c4 * 4 + 7], r1.w, s1);
            }
            out8[u] += s0 + s1;
        }
    }

    float* pp = partial + ((size_t)tg * BATCH + b) * UNITS + uh * 8;
    *(float4*)&pp[0] = *(float4*)&out8[0];
    *(float4*)&pp[4] = *(float4*)&out8[4];
}

// ---------------------------------------------------------------------------
// reduce over NTG partials, scale 1/NTREES. 1 wave/CU -> needs load ILP.
// ---------------------------------------------------------------------------
__global__ void reduce_kernel(const float* __restrict__ partial,
                              float* __restrict__ out) {
    int idx = blockIdx.x * 256 + threadIdx.x;          // 0..16383
    float s = 0.0f;
#pragma unroll 16
    for (int tg = 0; tg < NTG; ++tg)
        s += partial[(size_t)tg * BATCH * UNITS + idx];
    out[idx] = s * (1.0f / (float)NTREES);
}

// ---------------------------------------------------------------------------
extern "C" void kernel_launch(void* const* d_in, const int* in_sizes, int n_in,
                              void* d_out, int out_size, void* d_ws, size_t ws_size,
                              hipStream_t stream) {
    const float* x    = (const float*)d_in[0];
    const float* fsl  = (const float*)d_in[1];
    const float* thr  = (const float*)d_in[2];
    const float* lt   = (const float*)d_in[3];
    const float* resp = (const float*)d_in[4];
    float* out = (float*)d_out;
    float* ws  = (float*)d_ws;

    float* gates   = ws + WS_GATES;
    float* thrp    = ws + WS_THRP;
    float* selp    = ws + WS_SH;     // lifetime: prep -> gemm
    float* partial = ws + WS_SH;     // lifetime: tree -> reduce (overlay)

    prep_kernel<<<(DIM * NTREES) / 256 + 1, 256, 0, stream>>>(fsl, thr, lt, selp, thrp);
    gemm_gates<<<dim3(BATCH / GROWS, NCOLS / GCOLS), 256, 0, stream>>>(x, selp, thrp, gates);
    tree_kernel<<<NTG * 8, 256, 0, stream>>>(gates, resp, partial);
    reduce_kernel<<<(BATCH * UNITS) / 256, 256, 0, stream>>>(partial, out);
}

// Round 14
// 180.485 us; speedup vs baseline: 2.9324x; 1.0626x over previous
//
#include <hip/hip_runtime.h>
#include <hip/hip_bf16.h>

#define DEPTH   6
#define NLEAF   64
#define BATCH   1024
#define DIM     256
#define NTREES  512
#define UNITS   16
#define NCOLS   (NTREES*DEPTH)          // 3072

// ---- GEMM: LDS-free, software-pipelined B. wave = 16 rows x 64 cols ----
#define GKC   16                         // k-chunk (two reg banks, static idx)
#define GROWS 32                         // rows per block (2 wave-row-groups)
#define GCOLS 128                        // cols per block (2 wave-col-groups)

// ---- tree kernel ----
#define TPT   4                          // trees per thread
#define NTG   (NTREES/TPT)               // 128
#define RLSZ  (TPT*UNITS*NLEAF)          // 4096 floats = 16 KB LDS

// ws layout (floats): gates 12.6MB | thrp | selp/partial overlay (~21 MB total)
#define WS_GATES 0
#define WS_THRP  (WS_GATES + BATCH*NCOLS)
#define WS_SH    (WS_THRP + NCOLS)

// ---------------------------------------------------------------------------
// prep: sparsemax over depth axis of (dim, n_trees, depth), scaled by
// exp(-log_temp); tail block computes thrp = thr * exp(-log_temp).
// ---------------------------------------------------------------------------
__global__ void prep_kernel(const float* __restrict__ fsl,
                            const float* __restrict__ thr,
                            const float* __restrict__ lt,
                            float* __restrict__ selp,
                            float* __restrict__ thrp) {
    if (blockIdx.x == (DIM * NTREES) / 256) {          // tail: thrp
        for (int j = threadIdx.x; j < NCOLS; j += 256)
            thrp[j] = thr[j] * __expf(-lt[j]);
        return;
    }
    int t = blockIdx.x * 256 + threadIdx.x;            // t = i*NTREES + n
    int n = t & (NTREES - 1);
    int base = t * DEPTH;

    float zv[DEPTH], zs[DEPTH];
#pragma unroll
    for (int d = 0; d < DEPTH; ++d) { zv[d] = fsl[base + d]; zs[d] = zv[d]; }

#pragma unroll
    for (int p = 0; p < DEPTH - 1; ++p)
#pragma unroll
        for (int j = 0; j < DEPTH - 1 - p; ++j) {
            float a = zs[j], b = zs[j + 1];
            zs[j] = fmaxf(a, b); zs[j + 1] = fminf(a, b);
        }

    float cs[DEPTH];
    cs[0] = zs[0];
#pragma unroll
    for (int d = 1; d < DEPTH; ++d) cs[d] = cs[d - 1] + zs[d];

    int k = 0;
#pragma unroll
    for (int d = 0; d < DEPTH; ++d)
        if (zs[d] * (float)(d + 1) > cs[d] - 1.0f) k++;

    float csk = cs[0];
#pragma unroll
    for (int d = 0; d < DEPTH; ++d) csk = (k - 1 == d) ? cs[d] : csk;
    float tau = (csk - 1.0f) / (float)k;

#pragma unroll
    for (int d = 0; d < DEPTH; ++d) {
        float it = __expf(-lt[n * DEPTH + d]);
        selp[base + d] = fmaxf(zv[d] - tau, 0.0f) * it;
    }
}

// ---------------------------------------------------------------------------
// gemm_gates v4: LDS-free + software-pipelined B.
// Wave-uniform rows (A scalarizable); lane-indexed cols (B coalesced).
// Two static b-banks: next chunk's 16 loads issue before current chunk's
// 256 FMAs -> per-wave latency hiding independent of occupancy.
// launch_bounds(256,3): cap ~84 > demand ~60, no spill (r7/r8 calibration).
// ---------------------------------------------------------------------------
__global__ __launch_bounds__(256, 3)
void gemm_gates(const float* __restrict__ x,
                const float* __restrict__ selp,
                const float* __restrict__ thrp,
                float* __restrict__ gates) {
    const int tid  = threadIdx.x;
    const int lane = tid & 63;
    const int w    = __builtin_amdgcn_readfirstlane(tid >> 6);   // wave 0..3
    const int m0   = blockIdx.x * GROWS + (w >> 1) * 16;         // wave's rows
    const int col  = blockIdx.y * GCOLS + (w & 1) * 64 + lane;   // lane's col

    float acc[16];
#pragma unroll
    for (int r = 0; r < 16; ++r) acc[r] = 0.0f;

    float bA[GKC], bB[GKC];

#define LOADB(B_, KC_)                                                         \
    _Pragma("unroll")                                                          \
    for (int k = 0; k < GKC; ++k)                                              \
        B_[k] = selp[(size_t)((KC_) * GKC + k) * NCOLS + col];
#define FMAS(B_, KC_)                                                          \
    _Pragma("unroll")                                                          \
    for (int r = 0; r < 16; ++r) {                                             \
        const float* ap = &x[(size_t)(m0 + r) * DIM + (KC_) * GKC];            \
        _Pragma("unroll")                                                      \
        for (int k = 0; k < GKC; ++k)                                          \
            acc[r] = fmaf(ap[k], B_[k], acc[r]);                               \
    }

    LOADB(bA, 0)
    for (int kc = 0; kc < DIM / GKC; kc += 2) {        // 16 chunks, 8 iters
        LOADB(bB, kc + 1)                              // prefetch odd chunk
        FMAS(bA, kc)
        if (kc + 2 < DIM / GKC) LOADB(bA, kc + 2)      // prefetch next even
        FMAS(bB, kc + 1)
    }
#undef LOADB
#undef FMAS

    // epilogue: sparsemoid + coalesced store
    const float th = thrp[col];
#pragma unroll
    for (int r = 0; r < 16; ++r) {
        float tl = acc[r] - th;
        float g  = fminf(fmaxf(fmaf(0.5f, tl, 0.5f), 0.0f), 1.0f);
        gates[(size_t)(m0 + r) * NCOLS + col] = g;
    }
}

// ---------------------------------------------------------------------------
// tree_kernel v2: resp staged in LDS (16 KB/block, coalesced fill, one
// barrier), then matvec reads LDS with wave-uniform addr (broadcast,
// conflict-free, lgkmcnt-pipelined) -> no global resp loads in hot loop.
// bc = bid&7 pins each XCD to one gates slice (1.5MB) in its L2.
// ---------------------------------------------------------------------------
__global__ __launch_bounds__(256, 2)
void tree_kernel(const float* __restrict__ gates,
                 const float* __restrict__ resp,
                 float* __restrict__ partial) {
    __shared__ float rl[RLSZ];                         // [t][u][c]

    const int bid  = blockIdx.x;
    const int bc   = bid & 7;                          // batch slice (XCD-pinned)
    const int tg   = bid >> 3;                         // tree group 0..127
    const int tid  = threadIdx.x;
    const int uh   = __builtin_amdgcn_readfirstlane((tid >> 6) & 1);
    const int b    = bc * 128 + (tid >> 7) * 64 + (tid & 63);

    // stage resp slice: 1024 float4, coalesced
    {
        const float4* rg = (const float4*)(resp + (size_t)tg * RLSZ);
        float4* rl4 = (float4*)rl;
#pragma unroll
        for (int i = 0; i < RLSZ / 4 / 256; ++i)
            rl4[tid + i * 256] = rg[tid + i * 256];
    }
    __syncthreads();

    const float* gp = gates + (size_t)b * NCOLS + tg * (TPT * DEPTH);

    float out8[8];
#pragma unroll
    for (int u = 0; u < 8; ++u) out8[u] = 0.0f;

#pragma unroll
    for (int t = 0; t < TPT; ++t) {
        // per-tree gate load: 3x float2 (8B-aligned at t*24B)
        float g[DEPTH];
#pragma unroll
        for (int i = 0; i < 3; ++i)
            *(float2*)&g[i * 2] = *(const float2*)&gp[t * DEPTH + i * 2];

        // leaf probabilities, fully static indexing
        float p[NLEAF];
        p[0] = 1.0f;
#pragma unroll
        for (int d = 0; d < DEPTH; ++d) {
            int w = 1 << d;
            float gd = g[d], hd = 1.0f - gd;
#pragma unroll
            for (int c = w - 1; c >= 0; --c) {
                float base = p[c];
                p[c + w] = base * hd;
                p[c]     = base * gd;
            }
        }

        // response matvec from LDS (uniform addr -> broadcast, no conflicts)
#pragma unroll
        for (int u = 0; u < 8; ++u) {
            const float* rp = &rl[(t * UNITS + uh * 8 + u) * NLEAF];
            float s0 = 0.0f, s1 = 0.0f;
#pragma unroll
            for (int c4 = 0; c4 < 16; c4 += 2) {
                float4 r0 = *(const float4*)&rp[c4 * 4];
                float4 r1 = *(const float4*)&rp[c4 * 4 + 4];
                s0 = fmaf(p[c4 * 4 + 0], r0.x, s0);
                s0 = fmaf(p[c4 * 4 + 1], r0.y, s0);
                s0 = fmaf(p[c4 * 4 + 2], r0.z, s0);
                s0 = fmaf(p[c4 * 4 + 3], r0.w, s0);
                s1 = fmaf(p[c4 * 4 + 4], r1.x, s1);
                s1 = fmaf(p[c4 * 4 + 5], r1.y, s1);
                s1 = fmaf(p[c4 * 4 + 6], r1.z, s1);
                s1 = fmaf(p[c4 * 4 + 7], r1.w, s1);
            }
            out8[u] += s0 + s1;
        }
    }

    float* pp = partial + ((size_t)tg * BATCH + b) * UNITS + uh * 8;
    *(float4*)&pp[0] = *(float4*)&out8[0];
    *(float4*)&pp[4] = *(float4*)&out8[4];
}

// ---------------------------------------------------------------------------
// reduce over NTG partials, scale 1/NTREES.
// ---------------------------------------------------------------------------
__global__ void reduce_kernel(const float* __restrict__ partial,
                              float* __restrict__ out) {
    int idx = blockIdx.x * 256 + threadIdx.x;          // 0..16383
    float s = 0.0f;
#pragma unroll 16
    for (int tg = 0; tg < NTG; ++tg)
        s += partial[(size_t)tg * BATCH * UNITS + idx];
    out[idx] = s * (1.0f / (float)NTREES);
}

// ---------------------------------------------------------------------------
extern "C" void kernel_launch(void* const* d_in, const int* in_sizes, int n_in,
                              void* d_out, int out_size, void* d_ws, size_t ws_size,
                              hipStream_t stream) {
    const float* x    = (const float*)d_in[0];
    const float* fsl  = (const float*)d_in[1];
    const float* thr  = (const float*)d_in[2];
    const float* lt   = (const float*)d_in[3];
    const float* resp = (const float*)d_in[4];
    float* out = (float*)d_out;
    float* ws  = (float*)d_ws;

    float* gates   = ws + WS_GATES;
    float* thrp    = ws + WS_THRP;
    float* selp    = ws + WS_SH;     // lifetime: prep -> gemm
    float* partial = ws + WS_SH;     // lifetime: tree -> reduce (overlay)

    prep_kernel<<<(DIM * NTREES) / 256 + 1, 256, 0, stream>>>(fsl, thr, lt, selp, thrp);
    gemm_gates<<<dim3(BATCH / GROWS, NCOLS / GCOLS), 256, 0, stream>>>(x, selp, thrp, gates);
    tree_kernel<<<NTG * 8, 256, 0, stream>>>(gates, resp, partial);
    reduce_kernel<<<(BATCH * UNITS) / 256, 256, 0, stream>>>(partial, out);
}